// Round 10
// baseline (492.961 us; speedup 1.0000x reference)
//
#include <hip/hip_runtime.h>

#define NBATCH 32
#define NG 32
#define CPG 16
#define LEN 4096
#define NC 512
#define MLEN 65536
#define K1_NB 64          // chunks per batch in stats kernel
#define K1_COLS 1024      // columns (m) per chunk
#define K1_TC 256         // tile columns

// workspace layout (in floats)
#define WS_CROSS 0
#define WS_SUMS  (NBATCH * K1_NB * 1024)           // 2097152
#define WS_WM    (WS_SUMS + NBATCH * K1_NB * 32)   // 2162688 (holds wm^T)
#define WS_MC    (WS_WM + NBATCH * 1024)           // 2195456
#define WS_CNT   (WS_MC + NBATCH * 32)             // 2196480 (32 ints)

typedef short bf16x8 __attribute__((ext_vector_type(8)));
typedef float f32x16 __attribute__((ext_vector_type(16)));
typedef float f32x2  __attribute__((ext_vector_type(2)));

// round-to-nearest-even fp32 -> bf16 bits
__device__ __forceinline__ unsigned rne16(float f) {
    unsigned u = __builtin_bit_cast(unsigned, f);
    return (u + 0x7FFFu + ((u >> 16) & 1u)) >> 16;
}

__device__ __forceinline__ float4 mm32(const float* A, const float* Bm, int i, int j0) {
    float4 m4 = make_float4(0.f, 0.f, 0.f, 0.f);
#pragma unroll 8
    for (int k = 0; k < 32; ++k) {
        const float a = A[i * 32 + k];
        const float4 bv = *(const float4*)&Bm[k * 32 + j0];
        m4.x += a * bv.x; m4.y += a * bv.y; m4.z += a * bv.z; m4.w += a * bv.w;
    }
    return m4;
}

// ---------------------------------------------------------------------------
// Kernel 1 (MFMA + fused NS tail): per-chunk Gram partials via split-bf16
// MFMA (measured ~52 us), then the LAST block of each batch (atomic counter)
// reduces the 64 partials, trace-normalizes, runs Newton-Schulz x5, and
// emits wm^T and mconst. Writers: write -> __threadfence -> atomicAdd;
// winner: __threadfence (acquire) -> read. NS order fixed -> deterministic.
// ---------------------------------------------------------------------------
__global__ __launch_bounds__(256) void k1_stats(const float* __restrict__ x,
                                                float* __restrict__ cross_p,
                                                float* __restrict__ sums_p,
                                                float* __restrict__ wmT_out,
                                                float* __restrict__ mc_out,
                                                int* __restrict__ cnt) {
    __shared__ __align__(16) char sh[32768];   // staging / reduce / NS scratch
    __shared__ int last_flag;
    const int blk   = blockIdx.x;
    const int b     = blk >> 6;
    const int chunk = blk & 63;
    const int t     = threadIdx.x;
    const int m0 = chunk * K1_COLS;
    const int cl = m0 >> 12;
    const int l0 = m0 & 4095;
    const float* xb = x + (size_t)b * (NC * LEN) + (size_t)cl * LEN + l0;

    const int lane = t & 63;
    const int wv   = t >> 6;
    const int frow = lane & 31;
    const int kh   = lane >> 5;

    const float* xs = xb + (size_t)(wv * 8) * (CPG * LEN) + lane * 4;

    f32x16 acc_hh = {};
    f32x16 acc_x  = {};
    float sump[8] = {};

    char* hiT = sh;
    char* loT = sh + 16384;

    float4 vA[8], vB[8];

    auto LOADT = [&](float4* v, int tile) {
#pragma unroll
        for (int p = 0; p < 8; ++p)
            v[p] = *(const float4*)(xs + (size_t)p * (CPG * LEN) + tile * K1_TC);
    };
    auto STAGE = [&](const float4* v) {
#pragma unroll
        for (int p = 0; p < 8; ++p) {
            const float4 f = v[p];
            sump[p] += (f.x + f.y) + (f.z + f.w);
            const unsigned h0 = rne16(f.x), h1 = rne16(f.y);
            const unsigned h2 = rne16(f.z), h3 = rne16(f.w);
            const float r0 = f.x - __builtin_bit_cast(float, h0 << 16);
            const float r1 = f.y - __builtin_bit_cast(float, h1 << 16);
            const float r2 = f.z - __builtin_bit_cast(float, h2 << 16);
            const float r3 = f.w - __builtin_bit_cast(float, h3 << 16);
            uint2 hw, lw;
            hw.x = h0 | (h1 << 16);
            hw.y = h2 | (h3 << 16);
            lw.x = rne16(r0) | (rne16(r1) << 16);
            lw.y = rne16(r2) | (rne16(r3) << 16);
            const int off = ((wv * 8 + p) * 512 + lane * 8) ^ (p << 4);
            *(uint2*)(hiT + off) = hw;
            *(uint2*)(loT + off) = lw;
        }
    };
    auto MFMA_PHASE = [&]() {
#pragma unroll
        for (int s = 0; s < 4; ++s) {
            const int k0  = wv * 64 + s * 16;
            const int off = (frow * 512 + k0 * 2 + kh * 16) ^ ((frow & 7) << 4);
            const bf16x8 fh = *(const bf16x8*)(hiT + off);
            const bf16x8 fl = *(const bf16x8*)(loT + off);
            acc_hh = __builtin_amdgcn_mfma_f32_32x32x16_bf16(fh, fh, acc_hh, 0, 0, 0);
            acc_x  = __builtin_amdgcn_mfma_f32_32x32x16_bf16(fh, fl, acc_x, 0, 0, 0);
            acc_x  = __builtin_amdgcn_mfma_f32_32x32x16_bf16(fl, fh, acc_x, 0, 0, 0);
        }
    };

    LOADT(vA, 0);
    LOADT(vB, 1);
    STAGE(vA);
    __syncthreads();
    MFMA_PHASE();
    __syncthreads();
    LOADT(vA, 2);
    STAGE(vB);
    __syncthreads();
    MFMA_PHASE();
    __syncthreads();
    LOADT(vB, 3);
    STAGE(vA);
    __syncthreads();
    MFMA_PHASE();
    __syncthreads();
    STAGE(vB);
    __syncthreads();
    MFMA_PHASE();

    // ---- reduce wave partials -> per-chunk partials in workspace ----
    __syncthreads();
    float* red = (float*)sh;
    float* rs  = (float*)(sh + 16384);
#pragma unroll
    for (int r = 0; r < 16; ++r) {
        const int rowc = (r & 3) + 8 * (r >> 2) + 4 * kh;
        red[wv * 1024 + rowc * 32 + frow] = acc_hh[r] + acc_x[r];
    }
#pragma unroll
    for (int p = 0; p < 8; ++p) rs[(wv * 8 + p) * 65 + lane] = sump[p];
    __syncthreads();

    const int e0 = t * 4;
    {
        float4 s0 = *(float4*)(red + e0);
        const float4 s1 = *(float4*)(red + 1024 + e0);
        const float4 s2 = *(float4*)(red + 2048 + e0);
        const float4 s3 = *(float4*)(red + 3072 + e0);
        s0.x += s1.x + s2.x + s3.x;
        s0.y += s1.y + s2.y + s3.y;
        s0.z += s1.z + s2.z + s3.z;
        s0.w += s1.w + s2.w + s3.w;
        *(float4*)(cross_p + ((size_t)b * K1_NB + chunk) * 1024 + e0) = s0;
    }
    if (t < 32) {
        float ssum = 0.f;
#pragma unroll
        for (int k = 0; k < 64; ++k) ssum += rs[t * 65 + k];
        sums_p[((size_t)b * K1_NB + chunk) * 32 + t] = ssum;
    }

    // ---- last-block-per-batch: reduce + Newton-Schulz (was kernel 2) ----
    __threadfence();                       // release partials to device scope
    if (t == 0) last_flag = (atomicAdd(&cnt[b], 1) == K1_NB - 1);
    __syncthreads();
    if (!last_flag) return;
    __threadfence();                       // acquire: see all partials

    float* Sn   = (float*)sh;              // 1024
    float* P    = Sn + 1024;
    float* T1   = P + 1024;
    float* T2   = T1 + 1024;
    float* mean = T2 + 1024;               // 32
    float* sc   = mean + 32;               // 2
    const int i  = e0 >> 5;
    const int j0 = e0 & 31;

    float4 a4 = make_float4(0.f, 0.f, 0.f, 0.f);
    const float* cp = cross_p + (size_t)b * K1_NB * 1024;
#pragma unroll 8
    for (int ch = 0; ch < K1_NB; ++ch) {
        const float4 v = *(const float4*)&cp[ch * 1024 + e0];
        a4.x += v.x; a4.y += v.y; a4.z += v.z; a4.w += v.w;
    }
    if (t < 32) {
        float s = 0.f;
        const float* sp = sums_p + (size_t)b * K1_NB * 32;
#pragma unroll 8
        for (int ch = 0; ch < K1_NB; ++ch) s += sp[ch * 32 + t];
        mean[t] = s * (1.0f / MLEN);
    }
    __syncthreads();

    const float mi = mean[i];
    float sig[4];
    sig[0] = a4.x * (1.0f / MLEN) - mi * mean[j0 + 0];
    sig[1] = a4.y * (1.0f / MLEN) - mi * mean[j0 + 1];
    sig[2] = a4.z * (1.0f / MLEN) - mi * mean[j0 + 2];
    sig[3] = a4.w * (1.0f / MLEN) - mi * mean[j0 + 3];
#pragma unroll
    for (int k = 0; k < 4; ++k) Sn[e0 + k] = sig[k];
    __syncthreads();
    if (t == 0) {
        float tr = 0.f;
        for (int g = 0; g < 32; ++g) tr += Sn[g * 32 + g];
        const float ti = 1.0f / tr;
        sc[0] = ti;
        sc[1] = sqrtf(ti);
    }
    __syncthreads();
    const float ti = sc[0];
#pragma unroll
    for (int k = 0; k < 4; ++k) Sn[e0 + k] = sig[k] * ti;
#pragma unroll
    for (int k = 0; k < 4; ++k) P[e0 + k] = (i == j0 + k) ? 1.f : 0.f;
    __syncthreads();

    for (int itn = 0; itn < 5; ++itn) {
        float4 m4 = mm32(P, P, i, j0);
        *(float4*)&T1[e0] = m4;
        __syncthreads();
        m4 = mm32(T1, P, i, j0);
        *(float4*)&T2[e0] = m4;
        __syncthreads();
        m4 = mm32(T2, Sn, i, j0);
        *(float4*)&T1[e0] = m4;
        __syncthreads();
#pragma unroll
        for (int k = 0; k < 4; ++k) P[e0 + k] = 1.5f * P[e0 + k] - 0.5f * T1[e0 + k];
        __syncthreads();
    }
    const float sti = sc[1];
#pragma unroll
    for (int k = 0; k < 4; ++k)
        wmT_out[(size_t)b * 1024 + (j0 + k) * 32 + i] = P[e0 + k] * sti;
    if (t < 32) {
        float mc = 0.f;
#pragma unroll
        for (int h = 0; h < 32; ++h) mc += P[t * 32 + h] * mean[h];
        mc_out[b * 32 + t] = mc * sti;
    }
}

// ---------------------------------------------------------------------------
// Kernel 3: streaming h, acc over g; rotating weight rows (prefetch h+1) and
// x prefetch depth 2 (h+1, h+2 in flight). Non-temporal stores (out is
// write-once) keep L2 for the x streams.
// ---------------------------------------------------------------------------
__global__ __launch_bounds__(256, 4) void k3_apply2(const float* __restrict__ x,
                                                    const float* __restrict__ wmT,
                                                    const float* __restrict__ mc,
                                                    const float* __restrict__ weight,
                                                    const float* __restrict__ bias,
                                                    float* __restrict__ out) {
    const int blk = blockIdx.x;
    const int b   = blk >> 7;
    const int r   = blk & 127;
    const int cl  = r >> 3;
    const int q   = r & 7;
    const int t   = threadIdx.x;
    const int l   = q * 512 + t * 2;
    const size_t base = (size_t)b * (NC * LEN) + (size_t)cl * LEN + l;
    const float* xb = x + base;
    float* ob = out + base;

    float2 acc[32];
#pragma unroll
    for (int g = 0; g < 32; ++g) acc[g] = make_float2(0.f, 0.f);

    const float4* wb = (const float4*)(wmT + (size_t)b * 1024);

    float4 w[8];
#pragma unroll
    for (int j = 0; j < 8; ++j) w[j] = wb[j];
    float2 xh  = *(const float2*)xb;
    float2 xn1 = *(const float2*)(xb + (size_t)(CPG * LEN));

#pragma unroll 2
    for (int h = 0; h < 32; ++h) {
        const float2 xn2 = *(const float2*)(xb + (size_t)((h + 2) & 31) * (CPG * LEN));
        float4 wn[8];
        {
            const int hn = (h + 1) & 31;
#pragma unroll
            for (int j = 0; j < 8; ++j) wn[j] = wb[hn * 8 + j];
        }
#pragma unroll
        for (int j = 0; j < 8; ++j) {
            acc[j * 4 + 0].x += w[j].x * xh.x;  acc[j * 4 + 0].y += w[j].x * xh.y;
            acc[j * 4 + 1].x += w[j].y * xh.x;  acc[j * 4 + 1].y += w[j].y * xh.y;
            acc[j * 4 + 2].x += w[j].z * xh.x;  acc[j * 4 + 2].y += w[j].z * xh.y;
            acc[j * 4 + 3].x += w[j].w * xh.x;  acc[j * 4 + 3].y += w[j].w * xh.y;
        }
#pragma unroll
        for (int j = 0; j < 8; ++j) w[j] = wn[j];
        xh = xn1;
        xn1 = xn2;
    }

    const float* mcb = mc + b * 32;
#pragma unroll
    for (int g = 0; g < 32; ++g) {
        const float m  = mcb[g];
        const float wt = weight[g * CPG + cl];
        const float bs = bias[g * CPG + cl];
        f32x2 rr;
        rr.x = (acc[g].x - m) * wt + bs;
        rr.y = (acc[g].y - m) * wt + bs;
        __builtin_nontemporal_store(rr, (f32x2*)(ob + (size_t)g * (CPG * LEN)));
    }
}

extern "C" void kernel_launch(void* const* d_in, const int* in_sizes, int n_in,
                              void* d_out, int out_size, void* d_ws, size_t ws_size,
                              hipStream_t stream) {
    const float* x      = (const float*)d_in[0];
    const float* weight = (const float*)d_in[1];
    const float* bias   = (const float*)d_in[2];
    float* outp = (float*)d_out;
    float* wsf  = (float*)d_ws;
    float* cross_p = wsf + WS_CROSS;
    float* sums_p  = wsf + WS_SUMS;
    float* wmp     = wsf + WS_WM;    // holds wm^T
    float* mcp     = wsf + WS_MC;
    int*   cnt     = (int*)(wsf + WS_CNT);

    // zero the per-batch arrival counters (workspace is not re-poisoned
    // between graph replays; memset is graph-capturable)
    (void)hipMemsetAsync(cnt, 0, NBATCH * sizeof(int), stream);

    k1_stats<<<NBATCH * K1_NB, 256, 0, stream>>>(x, cross_p, sums_p, wmp, mcp, cnt);
    k3_apply2<<<NBATCH * 128, 256, 0, stream>>>(x, wmp, mcp, weight, bias, outp);
}

// Round 11
// 166.590 us; speedup vs baseline: 2.9591x; 2.9591x over previous
//
#include <hip/hip_runtime.h>

#define NBATCH 32
#define NG 32
#define CPG 16
#define LEN 4096
#define NC 512
#define MLEN 65536
#define K1_NB 64          // chunks per batch in stats kernel
#define K1_COLS 1024      // columns (m) per chunk
#define K1_TC 256         // tile columns

// workspace layout (in floats)
#define WS_CROSS 0
#define WS_SUMS  (NBATCH * K1_NB * 1024)           // 2097152
#define WS_WM    (WS_SUMS + NBATCH * K1_NB * 32)   // 2162688 (holds wm^T)
#define WS_MC    (WS_WM + NBATCH * 1024)           // 2195456

typedef short bf16x8 __attribute__((ext_vector_type(8)));
typedef float f32x16 __attribute__((ext_vector_type(16)));
typedef float f32x2  __attribute__((ext_vector_type(2)));

// round-to-nearest-even fp32 -> bf16 bits
__device__ __forceinline__ unsigned rne16(float f) {
    unsigned u = __builtin_bit_cast(unsigned, f);
    return (u + 0x7FFFu + ((u >> 16) & 1u)) >> 16;
}

// ---------------------------------------------------------------------------
// Kernel 1 (MFMA): row sums S[g] and Gram cross[g][h] over 1024 cols/block.
// Split-bf16: cross ~= hi.hi^T + hi.lo^T + lo.hi^T (ll term ~2^-18, dropped).
// Measured ~52 us (~81% of the 42.5 us HBM floor). NO device-scope fences:
// the r10 fused-NS experiment showed per-block __threadfence costs ~440 us
// (buffer_wbl2 L2-writeback per block on non-coherent multi-XCD L2s).
// ---------------------------------------------------------------------------
__global__ __launch_bounds__(256) void k1_stats(const float* __restrict__ x,
                                                float* __restrict__ cross_p,
                                                float* __restrict__ sums_p) {
    __shared__ __align__(16) char sh[32768];   // hi[16K] | lo[16K]; reused for reduce
    const int blk   = blockIdx.x;
    const int b     = blk >> 6;
    const int chunk = blk & 63;
    const int t     = threadIdx.x;
    const int m0 = chunk * K1_COLS;
    const int cl = m0 >> 12;
    const int l0 = m0 & 4095;
    const float* xb = x + (size_t)b * (NC * LEN) + (size_t)cl * LEN + l0;

    const int lane = t & 63;
    const int wv   = t >> 6;
    const int frow = lane & 31;
    const int kh   = lane >> 5;

    const float* xs = xb + (size_t)(wv * 8) * (CPG * LEN) + lane * 4;

    f32x16 acc_hh = {};
    f32x16 acc_x  = {};
    float sump[8] = {};

    char* hiT = sh;
    char* loT = sh + 16384;

    float4 vA[8], vB[8];

    auto LOADT = [&](float4* v, int tile) {
#pragma unroll
        for (int p = 0; p < 8; ++p)
            v[p] = *(const float4*)(xs + (size_t)p * (CPG * LEN) + tile * K1_TC);
    };
    auto STAGE = [&](const float4* v) {
#pragma unroll
        for (int p = 0; p < 8; ++p) {
            const float4 f = v[p];
            sump[p] += (f.x + f.y) + (f.z + f.w);
            const unsigned h0 = rne16(f.x), h1 = rne16(f.y);
            const unsigned h2 = rne16(f.z), h3 = rne16(f.w);
            const float r0 = f.x - __builtin_bit_cast(float, h0 << 16);
            const float r1 = f.y - __builtin_bit_cast(float, h1 << 16);
            const float r2 = f.z - __builtin_bit_cast(float, h2 << 16);
            const float r3 = f.w - __builtin_bit_cast(float, h3 << 16);
            uint2 hw, lw;
            hw.x = h0 | (h1 << 16);
            hw.y = h2 | (h3 << 16);
            lw.x = rne16(r0) | (rne16(r1) << 16);
            lw.y = rne16(r2) | (rne16(r3) << 16);
            const int off = ((wv * 8 + p) * 512 + lane * 8) ^ (p << 4);
            *(uint2*)(hiT + off) = hw;
            *(uint2*)(loT + off) = lw;
        }
    };
    auto MFMA_PHASE = [&]() {
#pragma unroll
        for (int s = 0; s < 4; ++s) {
            const int k0  = wv * 64 + s * 16;
            const int off = (frow * 512 + k0 * 2 + kh * 16) ^ ((frow & 7) << 4);
            const bf16x8 fh = *(const bf16x8*)(hiT + off);
            const bf16x8 fl = *(const bf16x8*)(loT + off);
            acc_hh = __builtin_amdgcn_mfma_f32_32x32x16_bf16(fh, fh, acc_hh, 0, 0, 0);
            acc_x  = __builtin_amdgcn_mfma_f32_32x32x16_bf16(fh, fl, acc_x, 0, 0, 0);
            acc_x  = __builtin_amdgcn_mfma_f32_32x32x16_bf16(fl, fh, acc_x, 0, 0, 0);
        }
    };

    LOADT(vA, 0);
    LOADT(vB, 1);
    STAGE(vA);
    __syncthreads();
    MFMA_PHASE();
    __syncthreads();
    LOADT(vA, 2);
    STAGE(vB);
    __syncthreads();
    MFMA_PHASE();
    __syncthreads();
    LOADT(vB, 3);
    STAGE(vA);
    __syncthreads();
    MFMA_PHASE();
    __syncthreads();
    STAGE(vB);
    __syncthreads();
    MFMA_PHASE();

    // ---- reduce wave partials ----
    __syncthreads();
    float* red = (float*)sh;
    float* rs  = (float*)(sh + 16384);
#pragma unroll
    for (int r = 0; r < 16; ++r) {
        const int rowc = (r & 3) + 8 * (r >> 2) + 4 * kh;
        red[wv * 1024 + rowc * 32 + frow] = acc_hh[r] + acc_x[r];
    }
#pragma unroll
    for (int p = 0; p < 8; ++p) rs[(wv * 8 + p) * 65 + lane] = sump[p];
    __syncthreads();

    const int e0 = t * 4;
    float4 s0 = *(float4*)(red + e0);
    const float4 s1 = *(float4*)(red + 1024 + e0);
    const float4 s2 = *(float4*)(red + 2048 + e0);
    const float4 s3 = *(float4*)(red + 3072 + e0);
    s0.x += s1.x + s2.x + s3.x;
    s0.y += s1.y + s2.y + s3.y;
    s0.z += s1.z + s2.z + s3.z;
    s0.w += s1.w + s2.w + s3.w;
    *(float4*)(cross_p + ((size_t)b * K1_NB + chunk) * 1024 + e0) = s0;
    if (t < 32) {
        float ssum = 0.f;
#pragma unroll
        for (int k = 0; k < 64; ++k) ssum += rs[t * 65 + k];
        sums_p[((size_t)b * K1_NB + chunk) * 32 + t] = ssum;
    }
}

// ---------------------------------------------------------------------------
// Kernel 2: reduce partials -> sigma, trace-normalize, Newton-Schulz x5,
// emit wm^T and mconst. Kernel boundary = the one amortized device fence.
// ---------------------------------------------------------------------------
__device__ __forceinline__ float4 mm32(const float* A, const float* Bm, int i, int j0) {
    float4 m4 = make_float4(0.f, 0.f, 0.f, 0.f);
#pragma unroll 8
    for (int k = 0; k < 32; ++k) {
        const float a = A[i * 32 + k];
        const float4 bv = *(const float4*)&Bm[k * 32 + j0];
        m4.x += a * bv.x; m4.y += a * bv.y; m4.z += a * bv.z; m4.w += a * bv.w;
    }
    return m4;
}

__global__ __launch_bounds__(256) void k2_ns(const float* __restrict__ cross_p,
                                             const float* __restrict__ sums_p,
                                             float* __restrict__ wmT_out,
                                             float* __restrict__ mc_out) {
    __shared__ __align__(16) float Sn[1024];
    __shared__ __align__(16) float P[1024];
    __shared__ __align__(16) float T1[1024];
    __shared__ __align__(16) float T2[1024];
    __shared__ float mean[32];
    __shared__ float sc[2];
    const int b  = blockIdx.x;
    const int t  = threadIdx.x;
    const int e0 = t * 4;
    const int i  = e0 >> 5;
    const int j0 = e0 & 31;

    float4 a4 = make_float4(0.f, 0.f, 0.f, 0.f);
    const float* cp = cross_p + (size_t)b * K1_NB * 1024;
#pragma unroll 8
    for (int ch = 0; ch < K1_NB; ++ch) {
        const float4 v = *(const float4*)&cp[ch * 1024 + e0];
        a4.x += v.x; a4.y += v.y; a4.z += v.z; a4.w += v.w;
    }
    if (t < 32) {
        float s = 0.f;
        const float* sp = sums_p + (size_t)b * K1_NB * 32;
#pragma unroll 8
        for (int ch = 0; ch < K1_NB; ++ch) s += sp[ch * 32 + t];
        mean[t] = s * (1.0f / MLEN);
    }
    __syncthreads();

    const float mi = mean[i];
    float sig[4];
    sig[0] = a4.x * (1.0f / MLEN) - mi * mean[j0 + 0];
    sig[1] = a4.y * (1.0f / MLEN) - mi * mean[j0 + 1];
    sig[2] = a4.z * (1.0f / MLEN) - mi * mean[j0 + 2];
    sig[3] = a4.w * (1.0f / MLEN) - mi * mean[j0 + 3];
#pragma unroll
    for (int k = 0; k < 4; ++k) Sn[e0 + k] = sig[k];
    __syncthreads();
    if (t == 0) {
        float tr = 0.f;
        for (int g = 0; g < 32; ++g) tr += Sn[g * 32 + g];
        const float ti = 1.0f / tr;
        sc[0] = ti;
        sc[1] = sqrtf(ti);
    }
    __syncthreads();
    const float ti = sc[0];
#pragma unroll
    for (int k = 0; k < 4; ++k) Sn[e0 + k] = sig[k] * ti;
#pragma unroll
    for (int k = 0; k < 4; ++k) P[e0 + k] = (i == j0 + k) ? 1.f : 0.f;
    __syncthreads();

    for (int itn = 0; itn < 5; ++itn) {
        float4 m4 = mm32(P, P, i, j0);
        *(float4*)&T1[e0] = m4;
        __syncthreads();
        m4 = mm32(T1, P, i, j0);
        *(float4*)&T2[e0] = m4;
        __syncthreads();
        m4 = mm32(T2, Sn, i, j0);
        *(float4*)&T1[e0] = m4;
        __syncthreads();
#pragma unroll
        for (int k = 0; k < 4; ++k) P[e0 + k] = 1.5f * P[e0 + k] - 0.5f * T1[e0 + k];
        __syncthreads();
    }
    const float sti = sc[1];
#pragma unroll
    for (int k = 0; k < 4; ++k)
        wmT_out[(size_t)b * 1024 + (j0 + k) * 32 + i] = P[e0 + k] * sti;
    if (t < 32) {
        float mc = 0.f;
#pragma unroll
        for (int h = 0; h < 32; ++h) mc += P[t * 32 + h] * mean[h];
        mc_out[b * 32 + t] = mc * sti;
    }
}

// ---------------------------------------------------------------------------
// Kernel 3: streaming h, acc over g; rotating weight rows (prefetch h+1) and
// x prefetch depth 2 (h+1, h+2 in flight). Non-temporal stores (out is
// write-once) keep L2 for the x streams. r8 depth-1 version measured 121 us.
// ---------------------------------------------------------------------------
__global__ __launch_bounds__(256, 4) void k3_apply2(const float* __restrict__ x,
                                                    const float* __restrict__ wmT,
                                                    const float* __restrict__ mc,
                                                    const float* __restrict__ weight,
                                                    const float* __restrict__ bias,
                                                    float* __restrict__ out) {
    const int blk = blockIdx.x;
    const int b   = blk >> 7;
    const int r   = blk & 127;
    const int cl  = r >> 3;
    const int q   = r & 7;
    const int t   = threadIdx.x;
    const int l   = q * 512 + t * 2;
    const size_t base = (size_t)b * (NC * LEN) + (size_t)cl * LEN + l;
    const float* xb = x + base;
    float* ob = out + base;

    float2 acc[32];
#pragma unroll
    for (int g = 0; g < 32; ++g) acc[g] = make_float2(0.f, 0.f);

    const float4* wb = (const float4*)(wmT + (size_t)b * 1024);

    float4 w[8];
#pragma unroll
    for (int j = 0; j < 8; ++j) w[j] = wb[j];
    float2 xh  = *(const float2*)xb;
    float2 xn1 = *(const float2*)(xb + (size_t)(CPG * LEN));

#pragma unroll 2
    for (int h = 0; h < 32; ++h) {
        const float2 xn2 = *(const float2*)(xb + (size_t)((h + 2) & 31) * (CPG * LEN));
        float4 wn[8];
        {
            const int hn = (h + 1) & 31;
#pragma unroll
            for (int j = 0; j < 8; ++j) wn[j] = wb[hn * 8 + j];
        }
#pragma unroll
        for (int j = 0; j < 8; ++j) {
            acc[j * 4 + 0].x += w[j].x * xh.x;  acc[j * 4 + 0].y += w[j].x * xh.y;
            acc[j * 4 + 1].x += w[j].y * xh.x;  acc[j * 4 + 1].y += w[j].y * xh.y;
            acc[j * 4 + 2].x += w[j].z * xh.x;  acc[j * 4 + 2].y += w[j].z * xh.y;
            acc[j * 4 + 3].x += w[j].w * xh.x;  acc[j * 4 + 3].y += w[j].w * xh.y;
        }
#pragma unroll
        for (int j = 0; j < 8; ++j) w[j] = wn[j];
        xh = xn1;
        xn1 = xn2;
    }

    const float* mcb = mc + b * 32;
#pragma unroll
    for (int g = 0; g < 32; ++g) {
        const float m  = mcb[g];
        const float wt = weight[g * CPG + cl];
        const float bs = bias[g * CPG + cl];
        f32x2 rr;
        rr.x = (acc[g].x - m) * wt + bs;
        rr.y = (acc[g].y - m) * wt + bs;
        __builtin_nontemporal_store(rr, (f32x2*)(ob + (size_t)g * (CPG * LEN)));
    }
}

extern "C" void kernel_launch(void* const* d_in, const int* in_sizes, int n_in,
                              void* d_out, int out_size, void* d_ws, size_t ws_size,
                              hipStream_t stream) {
    const float* x      = (const float*)d_in[0];
    const float* weight = (const float*)d_in[1];
    const float* bias   = (const float*)d_in[2];
    float* outp = (float*)d_out;
    float* wsf  = (float*)d_ws;
    float* cross_p = wsf + WS_CROSS;
    float* sums_p  = wsf + WS_SUMS;
    float* wmp     = wsf + WS_WM;    // holds wm^T
    float* mcp     = wsf + WS_MC;

    k1_stats<<<NBATCH * K1_NB, 256, 0, stream>>>(x, cross_p, sums_p);
    k2_ns<<<NBATCH, 256, 0, stream>>>(cross_p, sums_p, wmp, mcp);
    k3_apply2<<<NBATCH * 128, 256, 0, stream>>>(x, wmp, mcp, weight, bias, outp);
}

// Round 12
// 165.061 us; speedup vs baseline: 2.9865x; 1.0093x over previous
//
#include <hip/hip_runtime.h>

#define NBATCH 32
#define NG 32
#define CPG 16
#define LEN 4096
#define NC 512
#define MLEN 65536
#define K1_NB 64          // chunks per batch in stats kernel
#define K1_COLS 1024      // columns (m) per chunk
#define K1_TC 256         // tile columns

// workspace layout (in floats)
#define WS_CROSS 0
#define WS_SUMS  (NBATCH * K1_NB * 1024)           // 2097152
#define WS_WM    (WS_SUMS + NBATCH * K1_NB * 32)   // 2162688 (holds wm^T)
#define WS_MC    (WS_WM + NBATCH * 1024)           // 2195456

typedef short bf16x8 __attribute__((ext_vector_type(8)));
typedef float f32x16 __attribute__((ext_vector_type(16)));
typedef float f32x2  __attribute__((ext_vector_type(2)));

// round-to-nearest-even fp32 -> bf16 bits
__device__ __forceinline__ unsigned rne16(float f) {
    unsigned u = __builtin_bit_cast(unsigned, f);
    return (u + 0x7FFFu + ((u >> 16) & 1u)) >> 16;
}

// ---------------------------------------------------------------------------
// Kernel 1 (MFMA): row sums S[g] and Gram cross[g][h] over 1024 cols/block.
// Split-bf16: cross ~= hi.hi^T + hi.lo^T + lo.hi^T (ll term ~2^-18, dropped).
// Measured ~52 us. Ascending address order (pairs with K3's descending order
// for L3 alternating-direction scan reuse). NO device-scope fences (r10:
// per-block __threadfence = ~440 us of L2 writebacks on multi-XCD).
// ---------------------------------------------------------------------------
__global__ __launch_bounds__(256) void k1_stats(const float* __restrict__ x,
                                                float* __restrict__ cross_p,
                                                float* __restrict__ sums_p) {
    __shared__ __align__(16) char sh[32768];   // hi[16K] | lo[16K]; reused for reduce
    const int blk   = blockIdx.x;
    const int b     = blk >> 6;
    const int chunk = blk & 63;
    const int t     = threadIdx.x;
    const int m0 = chunk * K1_COLS;
    const int cl = m0 >> 12;
    const int l0 = m0 & 4095;
    const float* xb = x + (size_t)b * (NC * LEN) + (size_t)cl * LEN + l0;

    const int lane = t & 63;
    const int wv   = t >> 6;
    const int frow = lane & 31;
    const int kh   = lane >> 5;

    const float* xs = xb + (size_t)(wv * 8) * (CPG * LEN) + lane * 4;

    f32x16 acc_hh = {};
    f32x16 acc_x  = {};
    float sump[8] = {};

    char* hiT = sh;
    char* loT = sh + 16384;

    float4 vA[8], vB[8];

    auto LOADT = [&](float4* v, int tile) {
#pragma unroll
        for (int p = 0; p < 8; ++p)
            v[p] = *(const float4*)(xs + (size_t)p * (CPG * LEN) + tile * K1_TC);
    };
    auto STAGE = [&](const float4* v) {
#pragma unroll
        for (int p = 0; p < 8; ++p) {
            const float4 f = v[p];
            sump[p] += (f.x + f.y) + (f.z + f.w);
            const unsigned h0 = rne16(f.x), h1 = rne16(f.y);
            const unsigned h2 = rne16(f.z), h3 = rne16(f.w);
            const float r0 = f.x - __builtin_bit_cast(float, h0 << 16);
            const float r1 = f.y - __builtin_bit_cast(float, h1 << 16);
            const float r2 = f.z - __builtin_bit_cast(float, h2 << 16);
            const float r3 = f.w - __builtin_bit_cast(float, h3 << 16);
            uint2 hw, lw;
            hw.x = h0 | (h1 << 16);
            hw.y = h2 | (h3 << 16);
            lw.x = rne16(r0) | (rne16(r1) << 16);
            lw.y = rne16(r2) | (rne16(r3) << 16);
            const int off = ((wv * 8 + p) * 512 + lane * 8) ^ (p << 4);
            *(uint2*)(hiT + off) = hw;
            *(uint2*)(loT + off) = lw;
        }
    };
    auto MFMA_PHASE = [&]() {
#pragma unroll
        for (int s = 0; s < 4; ++s) {
            const int k0  = wv * 64 + s * 16;
            const int off = (frow * 512 + k0 * 2 + kh * 16) ^ ((frow & 7) << 4);
            const bf16x8 fh = *(const bf16x8*)(hiT + off);
            const bf16x8 fl = *(const bf16x8*)(loT + off);
            acc_hh = __builtin_amdgcn_mfma_f32_32x32x16_bf16(fh, fh, acc_hh, 0, 0, 0);
            acc_x  = __builtin_amdgcn_mfma_f32_32x32x16_bf16(fh, fl, acc_x, 0, 0, 0);
            acc_x  = __builtin_amdgcn_mfma_f32_32x32x16_bf16(fl, fh, acc_x, 0, 0, 0);
        }
    };

    LOADT(vA, 0);
    LOADT(vB, 1);
    STAGE(vA);
    __syncthreads();
    MFMA_PHASE();
    __syncthreads();
    LOADT(vA, 2);
    STAGE(vB);
    __syncthreads();
    MFMA_PHASE();
    __syncthreads();
    LOADT(vB, 3);
    STAGE(vA);
    __syncthreads();
    MFMA_PHASE();
    __syncthreads();
    STAGE(vB);
    __syncthreads();
    MFMA_PHASE();

    // ---- reduce wave partials ----
    __syncthreads();
    float* red = (float*)sh;
    float* rs  = (float*)(sh + 16384);
#pragma unroll
    for (int r = 0; r < 16; ++r) {
        const int rowc = (r & 3) + 8 * (r >> 2) + 4 * kh;
        red[wv * 1024 + rowc * 32 + frow] = acc_hh[r] + acc_x[r];
    }
#pragma unroll
    for (int p = 0; p < 8; ++p) rs[(wv * 8 + p) * 65 + lane] = sump[p];
    __syncthreads();

    const int e0 = t * 4;
    float4 s0 = *(float4*)(red + e0);
    const float4 s1 = *(float4*)(red + 1024 + e0);
    const float4 s2 = *(float4*)(red + 2048 + e0);
    const float4 s3 = *(float4*)(red + 3072 + e0);
    s0.x += s1.x + s2.x + s3.x;
    s0.y += s1.y + s2.y + s3.y;
    s0.z += s1.z + s2.z + s3.z;
    s0.w += s1.w + s2.w + s3.w;
    *(float4*)(cross_p + ((size_t)b * K1_NB + chunk) * 1024 + e0) = s0;
    if (t < 32) {
        float ssum = 0.f;
#pragma unroll
        for (int k = 0; k < 64; ++k) ssum += rs[t * 65 + k];
        sums_p[((size_t)b * K1_NB + chunk) * 32 + t] = ssum;
    }
}

// ---------------------------------------------------------------------------
// Kernel 2: reduce partials -> sigma, trace-normalize, Newton-Schulz x5,
// emit wm^T and mconst. Kernel boundary = the one amortized device fence.
// ---------------------------------------------------------------------------
__device__ __forceinline__ float4 mm32(const float* A, const float* Bm, int i, int j0) {
    float4 m4 = make_float4(0.f, 0.f, 0.f, 0.f);
#pragma unroll 8
    for (int k = 0; k < 32; ++k) {
        const float a = A[i * 32 + k];
        const float4 bv = *(const float4*)&Bm[k * 32 + j0];
        m4.x += a * bv.x; m4.y += a * bv.y; m4.z += a * bv.z; m4.w += a * bv.w;
    }
    return m4;
}

__global__ __launch_bounds__(256) void k2_ns(const float* __restrict__ cross_p,
                                             const float* __restrict__ sums_p,
                                             float* __restrict__ wmT_out,
                                             float* __restrict__ mc_out) {
    __shared__ __align__(16) float Sn[1024];
    __shared__ __align__(16) float P[1024];
    __shared__ __align__(16) float T1[1024];
    __shared__ __align__(16) float T2[1024];
    __shared__ float mean[32];
    __shared__ float sc[2];
    const int b  = blockIdx.x;
    const int t  = threadIdx.x;
    const int e0 = t * 4;
    const int i  = e0 >> 5;
    const int j0 = e0 & 31;

    float4 a4 = make_float4(0.f, 0.f, 0.f, 0.f);
    const float* cp = cross_p + (size_t)b * K1_NB * 1024;
#pragma unroll 8
    for (int ch = 0; ch < K1_NB; ++ch) {
        const float4 v = *(const float4*)&cp[ch * 1024 + e0];
        a4.x += v.x; a4.y += v.y; a4.z += v.z; a4.w += v.w;
    }
    if (t < 32) {
        float s = 0.f;
        const float* sp = sums_p + (size_t)b * K1_NB * 32;
#pragma unroll 8
        for (int ch = 0; ch < K1_NB; ++ch) s += sp[ch * 32 + t];
        mean[t] = s * (1.0f / MLEN);
    }
    __syncthreads();

    const float mi = mean[i];
    float sig[4];
    sig[0] = a4.x * (1.0f / MLEN) - mi * mean[j0 + 0];
    sig[1] = a4.y * (1.0f / MLEN) - mi * mean[j0 + 1];
    sig[2] = a4.z * (1.0f / MLEN) - mi * mean[j0 + 2];
    sig[3] = a4.w * (1.0f / MLEN) - mi * mean[j0 + 3];
#pragma unroll
    for (int k = 0; k < 4; ++k) Sn[e0 + k] = sig[k];
    __syncthreads();
    if (t == 0) {
        float tr = 0.f;
        for (int g = 0; g < 32; ++g) tr += Sn[g * 32 + g];
        const float ti = 1.0f / tr;
        sc[0] = ti;
        sc[1] = sqrtf(ti);
    }
    __syncthreads();
    const float ti = sc[0];
#pragma unroll
    for (int k = 0; k < 4; ++k) Sn[e0 + k] = sig[k] * ti;
#pragma unroll
    for (int k = 0; k < 4; ++k) P[e0 + k] = (i == j0 + k) ? 1.f : 0.f;
    __syncthreads();

    for (int itn = 0; itn < 5; ++itn) {
        float4 m4 = mm32(P, P, i, j0);
        *(float4*)&T1[e0] = m4;
        __syncthreads();
        m4 = mm32(T1, P, i, j0);
        *(float4*)&T2[e0] = m4;
        __syncthreads();
        m4 = mm32(T2, Sn, i, j0);
        *(float4*)&T1[e0] = m4;
        __syncthreads();
#pragma unroll
        for (int k = 0; k < 4; ++k) P[e0 + k] = 1.5f * P[e0 + k] - 0.5f * T1[e0 + k];
        __syncthreads();
    }
    const float sti = sc[1];
#pragma unroll
    for (int k = 0; k < 4; ++k)
        wmT_out[(size_t)b * 1024 + (j0 + k) * 32 + i] = P[e0 + k] * sti;
    if (t < 32) {
        float mc = 0.f;
#pragma unroll
        for (int h = 0; h < 32; ++h) mc += P[t * 32 + h] * mean[h];
        mc_out[b * 32 + t] = mc * sti;
    }
}

// ---------------------------------------------------------------------------
// Kernel 3: streaming h, acc over g; rotating weight rows (prefetch h+1),
// x prefetch depth 2, non-temporal stores. REVERSED block order: K1 just
// streamed x ascending through the 256MB L3 (x = 268MB); descending re-read
// starts on the most-recently-cached lines -> ~95% L3 hits instead of
// cyclic-scan thrash. nt out-stores don't allocate, so x stays resident.
// ---------------------------------------------------------------------------
__global__ __launch_bounds__(256, 4) void k3_apply2(const float* __restrict__ x,
                                                    const float* __restrict__ wmT,
                                                    const float* __restrict__ mc,
                                                    const float* __restrict__ weight,
                                                    const float* __restrict__ bias,
                                                    float* __restrict__ out) {
    const int blk = (NBATCH * 128 - 1) - blockIdx.x;   // descending address order
    const int b   = blk >> 7;
    const int r   = blk & 127;
    const int cl  = r >> 3;
    const int q   = r & 7;
    const int t   = threadIdx.x;
    const int l   = q * 512 + t * 2;
    const size_t base = (size_t)b * (NC * LEN) + (size_t)cl * LEN + l;
    const float* xb = x + base;
    float* ob = out + base;

    float2 acc[32];
#pragma unroll
    for (int g = 0; g < 32; ++g) acc[g] = make_float2(0.f, 0.f);

    const float4* wb = (const float4*)(wmT + (size_t)b * 1024);

    float4 w[8];
#pragma unroll
    for (int j = 0; j < 8; ++j) w[j] = wb[j];
    float2 xh  = *(const float2*)xb;
    float2 xn1 = *(const float2*)(xb + (size_t)(CPG * LEN));

#pragma unroll 2
    for (int h = 0; h < 32; ++h) {
        const float2 xn2 = *(const float2*)(xb + (size_t)((h + 2) & 31) * (CPG * LEN));
        float4 wn[8];
        {
            const int hn = (h + 1) & 31;
#pragma unroll
            for (int j = 0; j < 8; ++j) wn[j] = wb[hn * 8 + j];
        }
#pragma unroll
        for (int j = 0; j < 8; ++j) {
            acc[j * 4 + 0].x += w[j].x * xh.x;  acc[j * 4 + 0].y += w[j].x * xh.y;
            acc[j * 4 + 1].x += w[j].y * xh.x;  acc[j * 4 + 1].y += w[j].y * xh.y;
            acc[j * 4 + 2].x += w[j].z * xh.x;  acc[j * 4 + 2].y += w[j].z * xh.y;
            acc[j * 4 + 3].x += w[j].w * xh.x;  acc[j * 4 + 3].y += w[j].w * xh.y;
        }
#pragma unroll
        for (int j = 0; j < 8; ++j) w[j] = wn[j];
        xh = xn1;
        xn1 = xn2;
    }

    const float* mcb = mc + b * 32;
#pragma unroll
    for (int g = 0; g < 32; ++g) {
        const float m  = mcb[g];
        const float wt = weight[g * CPG + cl];
        const float bs = bias[g * CPG + cl];
        f32x2 rr;
        rr.x = (acc[g].x - m) * wt + bs;
        rr.y = (acc[g].y - m) * wt + bs;
        __builtin_nontemporal_store(rr, (f32x2*)(ob + (size_t)g * (CPG * LEN)));
    }
}

extern "C" void kernel_launch(void* const* d_in, const int* in_sizes, int n_in,
                              void* d_out, int out_size, void* d_ws, size_t ws_size,
                              hipStream_t stream) {
    const float* x      = (const float*)d_in[0];
    const float* weight = (const float*)d_in[1];
    const float* bias   = (const float*)d_in[2];
    float* outp = (float*)d_out;
    float* wsf  = (float*)d_ws;
    float* cross_p = wsf + WS_CROSS;
    float* sums_p  = wsf + WS_SUMS;
    float* wmp     = wsf + WS_WM;    // holds wm^T
    float* mcp     = wsf + WS_MC;

    k1_stats<<<NBATCH * K1_NB, 256, 0, stream>>>(x, cross_p, sums_p);
    k2_ns<<<NBATCH, 256, 0, stream>>>(cross_p, sums_p, wmp, mcp);
    k3_apply2<<<NBATCH * 128, 256, 0, stream>>>(x, wmp, mcp, weight, bias, outp);
}